// Round 3
// baseline (1235.177 us; speedup 1.0000x reference)
//
#include <hip/hip_runtime.h>
#include <math.h>

#define TPB 256
#define GTPB 192
#define ATPB 384

__device__ __forceinline__ float lrelu(float x){ return x > 0.f ? x : 0.2f*x; }

// ---------------- CSR build (graph constant across layers) ----------------
__global__ void k_init_cnt(int* __restrict__ cnt, int N){
  int t = blockIdx.x*TPB + threadIdx.x;
  if (t < 4*N) cnt[t] = (t < 3*N) ? 1 : 0;  // GAT counts start at 1 (self-loop)
}

__global__ void k_count(const int* __restrict__ ei, int* __restrict__ cnt, int N, int E){
  int t = blockIdx.x*TPB + threadIdx.x;
  if (t >= 3*E) return;
  int r = t / E, e = t - r*E;
  int dst = ei[(r*2+1)*E + e];
  atomicAdd(&cnt[r*N + dst], 1);
  atomicAdd(&cnt[3*N + dst], 1);
}

__global__ void k_scan4(const int* __restrict__ cnt, int* __restrict__ rp, int N){
  __shared__ int sh[1024];
  __shared__ int carry;
  int a = blockIdx.x;
  const int* c = cnt + a*N;
  int* r = rp + a*(N+1);
  if (threadIdx.x == 0) carry = 0;
  __syncthreads();
  for (int base = 0; base < N; base += 1024){
    int idx = base + threadIdx.x;
    int v = (idx < N) ? c[idx] : 0;
    sh[threadIdx.x] = v;
    __syncthreads();
    for (int off = 1; off < 1024; off <<= 1){
      int t = (threadIdx.x >= off) ? sh[threadIdx.x - off] : 0;
      __syncthreads();
      sh[threadIdx.x] += t;
      __syncthreads();
    }
    if (idx < N) r[idx] = carry + sh[threadIdx.x] - v;  // exclusive
    __syncthreads();
    if (threadIdx.x == 0) carry += sh[1023];
    __syncthreads();
  }
  if (threadIdx.x == 0) r[N] = carry;
}

__global__ void k_init_cursor(const int* __restrict__ rp, int* __restrict__ cur, int N){
  int t = blockIdx.x*TPB + threadIdx.x;
  if (t >= 4*N) return;
  int a = t / N, i = t - a*N;
  cur[t] = rp[a*(N+1) + i];
}

__global__ void k_scatter(const int* __restrict__ ei, int* __restrict__ cur,
                          int* __restrict__ idx_gat, int* __restrict__ idx_hgt,
                          int N, int E){
  int t = blockIdx.x*TPB + threadIdx.x;
  int EN = E + N;
  if (t < 3*E){
    int r = t / E, e = t - r*E;
    int src = ei[(r*2)*E + e];
    int dst = ei[(r*2+1)*E + e];
    int pg = atomicAdd(&cur[r*N + dst], 1);
    idx_gat[r*EN + pg] = src;
    int ph = atomicAdd(&cur[3*N + dst], 1);
    idx_hgt[ph] = r*N + src;           // packed (rel,src)
  } else if (t < 3*E + 3*N){
    int tt = t - 3*E;
    int r = tt / N, i = tt - r*N;
    int pg = atomicAdd(&cur[r*N + i], 1);
    idx_gat[r*EN + pg] = i;            // self loop
  }
}

// ---------------- LDS-tiled dense GEMM: C[mat] = A @ W[mat] (+ bias) ----------------
__global__ __launch_bounds__(GTPB) void k_gemm_t(const float* __restrict__ A,
                        const float* __restrict__ W,
                        const float* __restrict__ bias, float* __restrict__ C,
                        int n, int K){
  __shared__ float Wl[96*96];
  int mat = blockIdx.y;
  const float4* Wm4 = reinterpret_cast<const float4*>(W + (size_t)mat*K*96);
  for (int idx = threadIdx.x; idx < K*24; idx += GTPB)
    reinterpret_cast<float4*>(Wl)[idx] = Wm4[idx];
  __syncthreads();

  int cg = threadIdx.x % 12;
  int rg = threadIdx.x / 12;     // 0..15
  int c0 = cg*8;
  int r0 = blockIdx.x*96 + rg*6;

  float acc[6][8];
  #pragma unroll
  for (int u = 0; u < 6; u++)
    #pragma unroll
    for (int c = 0; c < 8; c++) acc[u][c] = 0.f;

  for (int k = 0; k < K; k += 4){
    float4 a[6];
    #pragma unroll
    for (int u = 0; u < 6; u++){
      int r = r0 + u;
      a[u] = (r < n) ? *reinterpret_cast<const float4*>(A + (size_t)r*K + k)
                     : make_float4(0.f,0.f,0.f,0.f);
    }
    #pragma unroll
    for (int kk = 0; kk < 4; kk++){
      float4 w0 = *reinterpret_cast<const float4*>(Wl + (k+kk)*96 + c0);
      float4 w1 = *reinterpret_cast<const float4*>(Wl + (k+kk)*96 + c0 + 4);
      float wv0 = w0.x, wv1 = w0.y, wv2 = w0.z, wv3 = w0.w;
      float wv4 = w1.x, wv5 = w1.y, wv6 = w1.z, wv7 = w1.w;
      #pragma unroll
      for (int u = 0; u < 6; u++){
        float av = (kk==0) ? a[u].x : (kk==1) ? a[u].y : (kk==2) ? a[u].z : a[u].w;
        acc[u][0] += av*wv0; acc[u][1] += av*wv1; acc[u][2] += av*wv2; acc[u][3] += av*wv3;
        acc[u][4] += av*wv4; acc[u][5] += av*wv5; acc[u][6] += av*wv6; acc[u][7] += av*wv7;
      }
    }
  }

  float b[8];
  if (bias){
    const float* bp = bias + mat*96 + c0;
    #pragma unroll
    for (int c = 0; c < 8; c++) b[c] = bp[c];
  } else {
    #pragma unroll
    for (int c = 0; c < 8; c++) b[c] = 0.f;
  }
  #pragma unroll
  for (int u = 0; u < 6; u++){
    int r = r0 + u;
    if (r < n){
      float* Cr = C + (size_t)mat*n*96 + (size_t)r*96 + c0;
      float4 o0 = make_float4(acc[u][0]+b[0], acc[u][1]+b[1], acc[u][2]+b[2], acc[u][3]+b[3]);
      float4 o1 = make_float4(acc[u][4]+b[4], acc[u][5]+b[5], acc[u][6]+b[6], acc[u][7]+b[7]);
      reinterpret_cast<float4*>(Cr)[0] = o0;
      reinterpret_cast<float4*>(Cr)[1] = o1;
    }
  }
}

// ---------------- GAT attention dots: a_src/a_dst [3,N,2] ----------------
__global__ void k_attdots(const float* __restrict__ hp, const float* __restrict__ att,
                          float* __restrict__ asrc, float* __restrict__ adst, int n){
  int t = blockIdx.x*TPB + threadIdx.x;
  if (t >= 3*n) return;
  int r = t / n;                       // t == r*n+i
  const float* row = hp + (size_t)t*96;
  const float* ap  = att + r*192;      // [2,2,48] per relation
  #pragma unroll
  for (int h = 0; h < 2; h++){
    float s = 0.f, d = 0.f;
    #pragma unroll 8
    for (int dd = 0; dd < 48; dd++){
      float v = row[h*48 + dd];
      s += v * ap[h*48 + dd];
      d += v * ap[96 + h*48 + dd];
    }
    asrc[t*2 + h] = s;
    adst[t*2 + h] = d;
  }
}

// ---------------- GAT softmax+aggregate: 96-lane group per (rel,node), online softmax ----
__global__ __launch_bounds__(ATPB) void k_gat_agg2(const float* __restrict__ asrc,
                          const float* __restrict__ adst,
                          const float* __restrict__ hp, const int* __restrict__ rowptr,
                          const int* __restrict__ idxg, float* __restrict__ outp,
                          int n, int Eplus){
  int g = blockIdx.x*(ATPB/96) + threadIdx.x/96;   // g = r*n + i
  if (g >= 3*n) return;
  int lane = threadIdx.x % 96;                      // lane = h*48 + f
  int r = (g >= 2*n) ? 2 : (g >= n ? 1 : 0);
  int i = g - r*n;
  int h = lane / 48;
  const int* rp = rowptr + r*(n+1);
  int s0 = rp[i], s1 = rp[i+1];
  const int* ix = idxg + (size_t)r*Eplus;
  const float* as = asrc + (size_t)r*n*2;
  float ad = adst[(size_t)g*2 + h];
  const float* hpb = hp + (size_t)r*n*96;
  float m = -1e30f, ssum = 0.f, acc = 0.f;
  for (int j = s0; j < s1; j++){
    int src = ix[j];
    float lg = lrelu(as[src*2 + h] + ad);
    float v  = hpb[(size_t)src*96 + lane];
    float mn = fmaxf(m, lg);
    float c  = __expf(m - mn);
    float e  = __expf(lg - mn);
    ssum = ssum*c + e;
    acc  = acc*c + e*v;
    m = mn;
  }
  outp[(size_t)g*96 + lane] = acc / ssum;   // self-loop guarantees non-empty
}

// ---------------- combine 3 relations + bias, accumulate BN stats ----------------
__global__ void k_combine_stats(const float* __restrict__ gout, const float* __restrict__ b3,
                                float* __restrict__ pre, float* __restrict__ stats, int total){
  __shared__ float s1[96], s2[96];
  if (threadIdx.x < 96){ s1[threadIdx.x] = 0.f; s2[threadIdx.x] = 0.f; }
  __syncthreads();
  int nh = total;
  int idx0 = blockIdx.x*TPB*8 + threadIdx.x;
  for (int it = 0; it < 8; it++){
    int idx = idx0 + it*TPB;
    if (idx < nh){
      int c = idx % 96;
      float v = gout[idx] + gout[(size_t)nh + idx] + gout[2*(size_t)nh + idx]
              + b3[c] + b3[96 + c] + b3[192 + c];
      pre[idx] = v;
      atomicAdd(&s1[c], v);
      atomicAdd(&s2[c], v*v);
    }
  }
  __syncthreads();
  if (threadIdx.x < 96){
    atomicAdd(&stats[threadIdx.x], s1[threadIdx.x]);
    atomicAdd(&stats[96 + threadIdx.x], s2[threadIdx.x]);
  }
}

// ---------------- HGT skip-mix in place + BN stats ----------------
__global__ void k_mix_stats(float* __restrict__ pre, const float* __restrict__ h,
                            const float* __restrict__ skip, float* __restrict__ stats, int total){
  __shared__ float s1[96], s2[96];
  if (threadIdx.x < 96){ s1[threadIdx.x] = 0.f; s2[threadIdx.x] = 0.f; }
  __syncthreads();
  float sk = 1.f / (1.f + expf(-skip[0]));
  int idx0 = blockIdx.x*TPB*8 + threadIdx.x;
  for (int it = 0; it < 8; it++){
    int idx = idx0 + it*TPB;
    if (idx < total){
      int c = idx % 96;
      float v = sk*pre[idx] + (1.f - sk)*h[idx];
      pre[idx] = v;
      atomicAdd(&s1[c], v);
      atomicAdd(&s2[c], v*v);
    }
  }
  __syncthreads();
  if (threadIdx.x < 96){
    atomicAdd(&stats[threadIdx.x], s1[threadIdx.x]);
    atomicAdd(&stats[96 + threadIdx.x], s2[threadIdx.x]);
  }
}

// ---------------- BN finalize ----------------
__global__ void k_bn_final(float* __restrict__ stats, const float* __restrict__ gamma,
                           const float* __restrict__ beta, int n){
  int c = threadIdx.x;
  if (c < 96){
    float fn = (float)n;
    float mean = stats[c] / fn;
    float var  = stats[96 + c] / fn - mean*mean;
    float iv   = rsqrtf(var + 1e-5f);
    float sc   = gamma[c] * iv;
    stats[192 + c] = sc;
    stats[288 + c] = beta[c] - mean*sc;
    stats[c] = 0.f;
    stats[96 + c] = 0.f;
  }
}

// ---------------- apply: h = lrelu(res*h + bn(pre) + inj) ----------------
__global__ void k_apply(float* __restrict__ h, const float* __restrict__ pre,
                        const float* __restrict__ stats, const float* __restrict__ inj,
                        int res, int total){
  int idx = blockIdx.x*TPB + threadIdx.x;
  if (idx >= total) return;
  int c = idx % 96;
  float v = stats[192 + c]*pre[idx] + stats[288 + c];
  if (inj) v += inj[idx];
  if (res) v += h[idx];
  h[idx] = lrelu(v);
}

// ---------------- HGT per-node K/V transforms: K_r = k·a_rel, V_r = v·m_rel ----------------
__global__ void k_kv(const float* __restrict__ kin, const float* __restrict__ vin,
                     const float* __restrict__ arel, const float* __restrict__ mrel,
                     float* __restrict__ Kb, float* __restrict__ Vb, int n){
  int t = blockIdx.x*TPB + threadIdx.x;
  if (t >= 3*n*96) return;
  int c = t % 96;
  int i = (t / 96) % n;
  int r = t / (96*n);
  int hh = c >> 4, f = c & 15;
  const float* kr = kin + (size_t)i*96 + hh*16;
  const float* vr = vin + (size_t)i*96 + hh*16;
  const float* ar = arel + (size_t)((r*6 + hh)*16)*16 + f;
  const float* mr = mrel + (size_t)((r*6 + hh)*16)*16 + f;
  float ka = 0.f, va = 0.f;
  #pragma unroll
  for (int d = 0; d < 16; d++){
    ka += kr[d] * ar[d*16];
    va += vr[d] * mr[d*16];
  }
  Kb[t] = ka;   // t == (r*n+i)*96+c
  Vb[t] = va;
}

// ---------------- HGT joint softmax+agg+GELU: 96-lane group per node, online softmax ----
__global__ __launch_bounds__(ATPB) void k_hgt_agg2(const float* __restrict__ qkv,
                          const float* __restrict__ Kb,
                          const float* __restrict__ Vb, const float* __restrict__ prel,
                          const int* __restrict__ rp4, const int* __restrict__ idxh,
                          float* __restrict__ gbuf, int n){
  int node = blockIdx.x*(ATPB/96) + threadIdx.x/96;
  if (node >= n) return;
  int lane = threadIdx.x % 96;                      // lane = h*16 + f
  int h = lane >> 4;
  float q = qkv[(size_t)n*96 + (size_t)node*96 + lane];
  float pp0 = 0.25f*prel[h], pp1 = 0.25f*prel[6+h], pp2 = 0.25f*prel[12+h];
  const int* rp = rp4 + 3*(n+1);
  int s0 = rp[node], s1 = rp[node+1];
  float m = -1e30f, ssum = 0.f, acc = 0.f;
  for (int j = s0; j < s1; j++){
    int packed = idxh[j];                           // r*n + src
    float kv = Kb[(size_t)packed*96 + lane];
    float dot = q*kv;
    dot += __shfl_xor(dot, 1);
    dot += __shfl_xor(dot, 2);
    dot += __shfl_xor(dot, 4);
    dot += __shfl_xor(dot, 8);
    float pp = (packed >= 2*n) ? pp2 : ((packed >= n) ? pp1 : pp0);
    float lg = dot * pp;
    float v  = Vb[(size_t)packed*96 + lane];
    float mn = fmaxf(m, lg);
    float c  = __expf(m - mn);
    float e  = __expf(lg - mn);
    ssum = ssum*c + e;
    acc  = acc*c + e*v;
    m = mn;
  }
  float x = (s1 > s0) ? acc/ssum : 0.f;
  gbuf[(size_t)node*96 + lane] = 0.5f*x*(1.f + erff(x*0.70710678118654752f));
}

// ---------------- final linear ----------------
__global__ void k_final_lin(const float* __restrict__ h, const float* __restrict__ w,
                            const float* __restrict__ b, float* __restrict__ out, int N){
  int i = blockIdx.x*TPB + threadIdx.x;
  if (i >= N) return;
  const float4* hr = reinterpret_cast<const float4*>(h + (size_t)i*96);
  const float4* wr = reinterpret_cast<const float4*>(w);
  float acc = 0.f;
  #pragma unroll
  for (int c = 0; c < 24; c++){
    float4 a = hr[c], q = wr[c];
    acc += a.x*q.x + a.y*q.y + a.z*q.z + a.w*q.w;
  }
  out[i] = acc + b[0];
}

// =====================================================================
extern "C" void kernel_launch(void* const* d_in, const int* in_sizes, int n_in,
                              void* d_out, int out_size, void* d_ws, size_t ws_size,
                              hipStream_t stream){
  const float* x        = (const float*)d_in[0];
  const int*   ei       = (const int*)  d_in[1];
  const float* gat0_W   = (const float*)d_in[2];
  const float* gat0_att = (const float*)d_in[3];
  const float* gat0_b   = (const float*)d_in[4];
  const float* gat_W    = (const float*)d_in[5];
  const float* gat_att  = (const float*)d_in[6];
  const float* gat_b    = (const float*)d_in[7];
  const float* bn_g     = (const float*)d_in[8];
  const float* bn_b     = (const float*)d_in[9];
  const float* kqv_W    = (const float*)d_in[10];
  const float* kqv_b    = (const float*)d_in[11];
  const float* a_rel    = (const float*)d_in[12];
  const float* m_rel    = (const float*)d_in[13];
  const float* p_rel    = (const float*)d_in[14];
  const float* hout_W   = (const float*)d_in[15];
  const float* hout_b   = (const float*)d_in[16];
  const float* skip     = (const float*)d_in[17];
  const float* proj_W   = (const float*)d_in[18];
  const float* proj_b   = (const float*)d_in[19];
  const float* lin_W    = (const float*)d_in[20];
  const float* lin_b    = (const float*)d_in[21];
  float* out = (float*)d_out;

  const int N = in_sizes[0] / 32;
  const int E = in_sizes[1] / 6;
  const size_t NH = (size_t)N * 96;
  const int nh = (int)NH;

  // ---- workspace layout (floats, then ints) ----
  float* f = (float*)d_ws;
  float* h_buf = f;  f += NH;
  float* pre   = f;  f += NH;
  float* b3a   = f;  f += 3*NH;      // hp (GAT) | Kb (HGT)
  float* b3b   = f;  f += 3*NH;      // per-rel GAT out | Vb (HGT)
  float* b3c   = f;  f += 3*NH;      // qkv (HGT)
  float* aux   = f;  f += NH;        // injection | gelu(agg)
  float* asrc  = f;  f += (size_t)3*N*2;
  float* adst  = f;  f += (size_t)3*N*2;
  float* stats = f;  f += 512;
  int* ip = (int*)f;
  int* cnt     = ip;  ip += 4*N;
  int* rowptr  = ip;  ip += 4*(N+1);
  int* cursor  = ip;  ip += 4*N;
  int* idx_gat = ip;  ip += 3*(E+N);
  int* idx_hgt = ip;  ip += 3*E;

  auto g1 = [](int n){ return dim3((n + TPB - 1)/TPB); };
  const int gx = (N + 95)/96;                 // GEMM row-tiles
  const dim3 gg(gx, 3);                       // 3-matrix GEMM grid
  const dim3 g1m(gx, 1);                      // 1-matrix GEMM grid
  const int cs_blocks = (nh + TPB*8 - 1)/(TPB*8);
  const int gat_blocks = (3*N + 3)/4;         // 4 groups of 96 per 384-block
  const int hgt_blocks = (N + 3)/4;

  // ---- CSR build ----
  hipMemsetAsync(stats, 0, 192*sizeof(float), stream);
  k_init_cnt   <<<g1(4*N),       TPB, 0, stream>>>(cnt, N);
  k_count      <<<g1(3*E),       TPB, 0, stream>>>(ei, cnt, N, E);
  k_scan4      <<<4,            1024, 0, stream>>>(cnt, rowptr, N);
  k_init_cursor<<<g1(4*N),       TPB, 0, stream>>>(rowptr, cursor, N);
  k_scatter    <<<g1(3*E+3*N),   TPB, 0, stream>>>(ei, cursor, idx_gat, idx_hgt, N, E);

  auto run_hgt = [&](int idx, int bnidx){
    k_gemm_t  <<<gg, GTPB, 0, stream>>>(h_buf, kqv_W + (size_t)idx*3*96*96, kqv_b + idx*3*96, b3c, N, 96);
    k_kv      <<<g1(3*nh), TPB, 0, stream>>>(b3c, b3c + 2*NH,
                                             a_rel + (size_t)idx*3*6*256,
                                             m_rel + (size_t)idx*3*6*256, b3a, b3b, N);
    k_hgt_agg2<<<hgt_blocks, ATPB, 0, stream>>>(b3c, b3a, b3b, p_rel + idx*18, rowptr, idx_hgt, aux, N);
    k_gemm_t  <<<g1m, GTPB, 0, stream>>>(aux, hout_W + (size_t)idx*96*96, hout_b + idx*96, pre, N, 96);
    k_mix_stats<<<cs_blocks, TPB, 0, stream>>>(pre, h_buf, skip + idx, stats, nh);
    k_bn_final<<<1, 128, 0, stream>>>(stats, bn_g + bnidx*96, bn_b + bnidx*96, N);
    k_apply   <<<g1(nh), TPB, 0, stream>>>(h_buf, pre, stats, nullptr, 1, nh);
  };

  // ---- GAT layer 0 (input dim 32, no residual) ----
  k_gemm_t       <<<gg, GTPB, 0, stream>>>(x, gat0_W, nullptr, b3a, N, 32);
  k_attdots      <<<g1(3*N), TPB, 0, stream>>>(b3a, gat0_att, asrc, adst, N);
  k_gat_agg2     <<<gat_blocks, ATPB, 0, stream>>>(asrc, adst, b3a, rowptr, idx_gat, b3b, N, E+N);
  k_combine_stats<<<cs_blocks, TPB, 0, stream>>>(b3b, gat0_b, pre, stats, nh);
  k_bn_final     <<<1, 128, 0, stream>>>(stats, bn_g, bn_b, N);
  k_apply        <<<g1(nh), TPB, 0, stream>>>(h_buf, pre, stats, nullptr, 0, nh);

  // ---- GAT layers 1..3 ----
  for (int i = 0; i < 3; i++){
    int li = i + 1;
    k_gemm_t       <<<gg, GTPB, 0, stream>>>(h_buf, gat_W + (size_t)i*3*96*96, nullptr, b3a, N, 96);
    k_attdots      <<<g1(3*N), TPB, 0, stream>>>(b3a, gat_att + i*3*192, asrc, adst, N);
    k_gat_agg2     <<<gat_blocks, ATPB, 0, stream>>>(asrc, adst, b3a, rowptr, idx_gat, b3b, N, E+N);
    k_combine_stats<<<cs_blocks, TPB, 0, stream>>>(b3b, gat_b + i*3*96, pre, stats, nh);
    k_bn_final     <<<1, 128, 0, stream>>>(stats, bn_g + (1+i)*96, bn_b + (1+i)*96, N);
    const float* inj = nullptr;
    if (li == 2 || li == 3){
      k_gemm_t<<<g1m, GTPB, 0, stream>>>(x, proj_W + (size_t)(li-2)*32*96, proj_b + (li-2)*96, aux, N, 32);
      inj = aux;
    }
    k_apply<<<g1(nh), TPB, 0, stream>>>(h_buf, pre, stats, inj, 1, nh);
    if (li == 1) run_hgt(0, 4);
  }
  run_hgt(1, 5);

  k_final_lin<<<g1(N), TPB, 0, stream>>>(h_buf, lin_W, lin_b, out, N);
}

// Round 4
// 1234.755 us; speedup vs baseline: 1.0003x; 1.0003x over previous
//
#include <hip/hip_runtime.h>
#include <math.h>

#define TPB 256
#define GTPB 192
#define ATPB 384

__device__ __forceinline__ float lrelu(float x){ return x > 0.f ? x : 0.2f*x; }

// ---------------- CSR build (graph constant across layers) ----------------
__global__ void k_init_cnt(int* __restrict__ cnt, int N){
  int t = blockIdx.x*TPB + threadIdx.x;
  if (t < 4*N) cnt[t] = (t < 3*N) ? 1 : 0;  // GAT counts start at 1 (self-loop)
}

__global__ void k_count(const int* __restrict__ ei, int* __restrict__ cnt, int N, int E){
  int t = blockIdx.x*TPB + threadIdx.x;
  if (t >= 3*E) return;
  int r = t / E, e = t - r*E;
  int dst = ei[(r*2+1)*E + e];
  atomicAdd(&cnt[r*N + dst], 1);
  atomicAdd(&cnt[3*N + dst], 1);
}

// scan + cursor init fused
__global__ void k_scan4(const int* __restrict__ cnt, int* __restrict__ rp,
                        int* __restrict__ cur, int N){
  __shared__ int sh[1024];
  __shared__ int carry;
  int a = blockIdx.x;
  const int* c = cnt + a*N;
  int* r = rp + a*(N+1);
  if (threadIdx.x == 0) carry = 0;
  __syncthreads();
  for (int base = 0; base < N; base += 1024){
    int idx = base + threadIdx.x;
    int v = (idx < N) ? c[idx] : 0;
    sh[threadIdx.x] = v;
    __syncthreads();
    for (int off = 1; off < 1024; off <<= 1){
      int t = (threadIdx.x >= off) ? sh[threadIdx.x - off] : 0;
      __syncthreads();
      sh[threadIdx.x] += t;
      __syncthreads();
    }
    if (idx < N){
      int ex = carry + sh[threadIdx.x] - v;   // exclusive
      r[idx] = ex;
      cur[a*N + idx] = ex;
    }
    __syncthreads();
    if (threadIdx.x == 0) carry += sh[1023];
    __syncthreads();
  }
  if (threadIdx.x == 0) r[N] = carry;
}

__global__ void k_scatter(const int* __restrict__ ei, int* __restrict__ cur,
                          int* __restrict__ idx_gat, int* __restrict__ idx_gat_dst,
                          int* __restrict__ idx_hgt, int* __restrict__ idx_hgt_dst,
                          int N, int E){
  int t = blockIdx.x*TPB + threadIdx.x;
  int EN = E + N;
  if (t < 3*E){
    int r = t / E, e = t - r*E;
    int src = ei[(r*2)*E + e];
    int dst = ei[(r*2+1)*E + e];
    int pg = atomicAdd(&cur[r*N + dst], 1);
    idx_gat[r*EN + pg] = src;
    idx_gat_dst[r*EN + pg] = dst;
    int ph = atomicAdd(&cur[3*N + dst], 1);
    idx_hgt[ph] = r*N + src;           // packed (rel,src)
    idx_hgt_dst[ph] = dst;
  } else if (t < 3*E + 3*N){
    int tt = t - 3*E;
    int r = tt / N, i = tt - r*N;
    int pg = atomicAdd(&cur[r*N + i], 1);
    idx_gat[r*EN + pg] = i;            // self loop
    idx_gat_dst[r*EN + pg] = i;
  }
}

// ---------------- LDS-tiled dense GEMM: C[mat] = A @ W[mat] (+ bias) ----------------
__global__ __launch_bounds__(GTPB) void k_gemm_t(const float* __restrict__ A,
                        const float* __restrict__ W,
                        const float* __restrict__ bias, float* __restrict__ C,
                        int n, int K){
  __shared__ float Wl[96*96];
  int mat = blockIdx.y;
  const float4* Wm4 = reinterpret_cast<const float4*>(W + (size_t)mat*K*96);
  for (int idx = threadIdx.x; idx < K*24; idx += GTPB)
    reinterpret_cast<float4*>(Wl)[idx] = Wm4[idx];
  __syncthreads();

  int cg = threadIdx.x % 12;
  int rg = threadIdx.x / 12;     // 0..15
  int c0 = cg*8;
  int r0 = blockIdx.x*96 + rg*6;

  float acc[6][8];
  #pragma unroll
  for (int u = 0; u < 6; u++)
    #pragma unroll
    for (int c = 0; c < 8; c++) acc[u][c] = 0.f;

  for (int k = 0; k < K; k += 4){
    float4 a[6];
    #pragma unroll
    for (int u = 0; u < 6; u++){
      int r = r0 + u;
      a[u] = (r < n) ? *reinterpret_cast<const float4*>(A + (size_t)r*K + k)
                     : make_float4(0.f,0.f,0.f,0.f);
    }
    #pragma unroll
    for (int kk = 0; kk < 4; kk++){
      float4 w0 = *reinterpret_cast<const float4*>(Wl + (k+kk)*96 + c0);
      float4 w1 = *reinterpret_cast<const float4*>(Wl + (k+kk)*96 + c0 + 4);
      float wv0 = w0.x, wv1 = w0.y, wv2 = w0.z, wv3 = w0.w;
      float wv4 = w1.x, wv5 = w1.y, wv6 = w1.z, wv7 = w1.w;
      #pragma unroll
      for (int u = 0; u < 6; u++){
        float av = (kk==0) ? a[u].x : (kk==1) ? a[u].y : (kk==2) ? a[u].z : a[u].w;
        acc[u][0] += av*wv0; acc[u][1] += av*wv1; acc[u][2] += av*wv2; acc[u][3] += av*wv3;
        acc[u][4] += av*wv4; acc[u][5] += av*wv5; acc[u][6] += av*wv6; acc[u][7] += av*wv7;
      }
    }
  }

  float b[8];
  if (bias){
    const float* bp = bias + mat*96 + c0;
    #pragma unroll
    for (int c = 0; c < 8; c++) b[c] = bp[c];
  } else {
    #pragma unroll
    for (int c = 0; c < 8; c++) b[c] = 0.f;
  }
  #pragma unroll
  for (int u = 0; u < 6; u++){
    int r = r0 + u;
    if (r < n){
      float* Cr = C + (size_t)mat*n*96 + (size_t)r*96 + c0;
      float4 o0 = make_float4(acc[u][0]+b[0], acc[u][1]+b[1], acc[u][2]+b[2], acc[u][3]+b[3]);
      float4 o1 = make_float4(acc[u][4]+b[4], acc[u][5]+b[5], acc[u][6]+b[6], acc[u][7]+b[7]);
      reinterpret_cast<float4*>(Cr)[0] = o0;
      reinterpret_cast<float4*>(Cr)[1] = o1;
    }
  }
}

// ---------------- GAT attention dots: a_src/a_dst [3,N,2] ----------------
__global__ void k_attdots(const float* __restrict__ hp, const float* __restrict__ att,
                          float* __restrict__ asrc, float* __restrict__ adst, int n){
  int t = blockIdx.x*TPB + threadIdx.x;
  if (t >= 3*n) return;
  int r = t / n;                       // t == r*n+i
  const float* row = hp + (size_t)t*96;
  const float* ap  = att + r*192;      // [2,2,48] per relation
  #pragma unroll
  for (int h = 0; h < 2; h++){
    float s = 0.f, d = 0.f;
    #pragma unroll 8
    for (int dd = 0; dd < 48; dd++){
      float v = row[h*48 + dd];
      s += v * ap[h*48 + dd];
      d += v * ap[96 + h*48 + dd];
    }
    asrc[t*2 + h] = s;
    adst[t*2 + h] = d;
  }
}

// ---------------- GAT phase A: per-slot edge weights (no max-sub softmax) ----------------
__global__ void k_gat_w(const float* __restrict__ asrc, const float* __restrict__ adst,
                        const int* __restrict__ idxg, const int* __restrict__ idxg_dst,
                        float* __restrict__ wbuf, int n, int EN){
  int s = blockIdx.x*TPB + threadIdx.x;
  if (s >= 3*EN) return;
  int r = s / EN;
  int src = idxg[s], dst = idxg_dst[s];
  const float2* as2 = reinterpret_cast<const float2*>(asrc) + (size_t)r*n;
  const float2* ad2 = reinterpret_cast<const float2*>(adst) + (size_t)r*n;
  float2 a_s = as2[src], a_d = ad2[dst];
  float w0 = __expf(fminf(lrelu(a_s.x + a_d.x), 80.f));
  float w1 = __expf(fminf(lrelu(a_s.y + a_d.y), 80.f));
  reinterpret_cast<float2*>(wbuf)[s] = make_float2(w0, w1);
}

// ---------------- GAT phase B: 96 lanes/(rel,node); plain weighted sum ----------------
__global__ __launch_bounds__(ATPB) void k_gat_agg3(const float* __restrict__ wbuf,
                          const float* __restrict__ hp, const int* __restrict__ rowptr,
                          const int* __restrict__ idxg, float* __restrict__ outp,
                          int n, int EN){
  int g = blockIdx.x*(ATPB/96) + threadIdx.x/96;   // g = r*n + i
  if (g >= 3*n) return;
  int lane = threadIdx.x % 96;                      // lane = h*48 + f
  int r = (g >= 2*n) ? 2 : (g >= n ? 1 : 0);
  int i = g - r*n;
  int h = lane / 48;
  const int* rp = rowptr + r*(n+1);
  int s0 = rp[i], s1 = rp[i+1];
  const int* ix = idxg + (size_t)r*EN;
  const float* wb = wbuf + (size_t)r*EN*2;
  const float* hpb = hp + (size_t)r*n*96;
  float ssum = 0.f, acc = 0.f;
  for (int j = s0; j < s1; j++){
    int src = ix[j];
    float w = wb[j*2 + h];
    ssum += w;
    acc  += w * hpb[(size_t)src*96 + lane];
  }
  outp[(size_t)g*96 + lane] = acc / ssum;   // self-loop guarantees non-empty
}

// ---------------- combine 3 relations + bias, accumulate BN stats ----------------
__global__ void k_combine_stats(const float* __restrict__ gout, const float* __restrict__ b3,
                                float* __restrict__ pre, float* __restrict__ stats, int total){
  __shared__ float s1[96], s2[96];
  if (threadIdx.x < 96){ s1[threadIdx.x] = 0.f; s2[threadIdx.x] = 0.f; }
  __syncthreads();
  int nh = total;
  int idx0 = blockIdx.x*TPB*8 + threadIdx.x;
  for (int it = 0; it < 8; it++){
    int idx = idx0 + it*TPB;
    if (idx < nh){
      int c = idx % 96;
      float v = gout[idx] + gout[(size_t)nh + idx] + gout[2*(size_t)nh + idx]
              + b3[c] + b3[96 + c] + b3[192 + c];
      pre[idx] = v;
      atomicAdd(&s1[c], v);
      atomicAdd(&s2[c], v*v);
    }
  }
  __syncthreads();
  if (threadIdx.x < 96){
    atomicAdd(&stats[threadIdx.x], s1[threadIdx.x]);
    atomicAdd(&stats[96 + threadIdx.x], s2[threadIdx.x]);
  }
}

// ---------------- HGT skip-mix in place + BN stats ----------------
__global__ void k_mix_stats(float* __restrict__ pre, const float* __restrict__ h,
                            const float* __restrict__ skip, float* __restrict__ stats, int total){
  __shared__ float s1[96], s2[96];
  if (threadIdx.x < 96){ s1[threadIdx.x] = 0.f; s2[threadIdx.x] = 0.f; }
  __syncthreads();
  float sk = 1.f / (1.f + expf(-skip[0]));
  int idx0 = blockIdx.x*TPB*8 + threadIdx.x;
  for (int it = 0; it < 8; it++){
    int idx = idx0 + it*TPB;
    if (idx < total){
      int c = idx % 96;
      float v = sk*pre[idx] + (1.f - sk)*h[idx];
      pre[idx] = v;
      atomicAdd(&s1[c], v);
      atomicAdd(&s2[c], v*v);
    }
  }
  __syncthreads();
  if (threadIdx.x < 96){
    atomicAdd(&stats[threadIdx.x], s1[threadIdx.x]);
    atomicAdd(&stats[96 + threadIdx.x], s2[threadIdx.x]);
  }
}

// ---------------- apply with inline BN finalize: h = lrelu(res*h + bn(pre) + inj) ----------------
__global__ void k_apply2(float* __restrict__ h, const float* __restrict__ pre,
                         const float* __restrict__ stats, const float* __restrict__ gamma,
                         const float* __restrict__ beta, const float* __restrict__ inj,
                         int res, int total, float inv_n){
  int idx = blockIdx.x*TPB + threadIdx.x;
  if (idx >= total) return;
  int c = idx % 96;
  float mean = stats[c] * inv_n;
  float var  = stats[96 + c] * inv_n - mean*mean;
  float sc   = gamma[c] * rsqrtf(var + 1e-5f);
  float sh   = beta[c] - mean*sc;
  float v = sc*pre[idx] + sh;
  if (inj) v += inj[idx];
  if (res) v += h[idx];
  h[idx] = lrelu(v);
}

// ---------------- HGT per-node K/V transforms: K_r = k·a_rel, V_r = v·m_rel ----------------
__global__ void k_kv(const float* __restrict__ kin, const float* __restrict__ vin,
                     const float* __restrict__ arel, const float* __restrict__ mrel,
                     float* __restrict__ Kb, float* __restrict__ Vb, int n){
  int t = blockIdx.x*TPB + threadIdx.x;
  if (t >= 3*n*96) return;
  int c = t % 96;
  int i = (t / 96) % n;
  int r = t / (96*n);
  int hh = c >> 4, f = c & 15;
  const float* kr = kin + (size_t)i*96 + hh*16;
  const float* vr = vin + (size_t)i*96 + hh*16;
  const float* ar = arel + (size_t)((r*6 + hh)*16)*16 + f;
  const float* mr = mrel + (size_t)((r*6 + hh)*16)*16 + f;
  float ka = 0.f, va = 0.f;
  #pragma unroll
  for (int d = 0; d < 16; d++){
    ka += kr[d] * ar[d*16];
    va += vr[d] * mr[d*16];
  }
  Kb[t] = ka;   // t == (r*n+i)*96+c
  Vb[t] = va;
}

// ---------------- HGT phase A: per-(slot,head) edge weights ----------------
__global__ void k_hgt_w(const float* __restrict__ qkv, const float* __restrict__ Kb,
                        const float* __restrict__ prel, const int* __restrict__ idxh,
                        const int* __restrict__ idxh_dst, float* __restrict__ wbuf,
                        int n, int totE){
  int t = blockIdx.x*TPB + threadIdx.x;
  if (t >= totE*6) return;
  int slot = t / 6, h = t - slot*6;
  int packed = idxh[slot];
  int dst = idxh_dst[slot];
  int r = (packed >= 2*n) ? 2 : (packed >= n ? 1 : 0);
  float pp = 0.25f * prel[r*6 + h];
  const float4* kp = reinterpret_cast<const float4*>(Kb + (size_t)packed*96 + h*16);
  const float4* qp = reinterpret_cast<const float4*>(qkv + (size_t)n*96 + (size_t)dst*96 + h*16);
  float dot = 0.f;
  #pragma unroll
  for (int w = 0; w < 4; w++){
    float4 kv = kp[w], qv = qp[w];
    dot += kv.x*qv.x + kv.y*qv.y + kv.z*qv.z + kv.w*qv.w;
  }
  wbuf[t] = __expf(fminf(dot*pp, 80.f));
}

// ---------------- HGT phase B: 96 lanes/node; weighted sum + GELU ----------------
__global__ __launch_bounds__(ATPB) void k_hgt_agg3(const float* __restrict__ wbuf,
                          const float* __restrict__ Vb,
                          const int* __restrict__ rp4, const int* __restrict__ idxh,
                          float* __restrict__ gbuf, int n){
  int node = blockIdx.x*(ATPB/96) + threadIdx.x/96;
  if (node >= n) return;
  int lane = threadIdx.x % 96;                      // lane = h*16 + f
  int h = lane >> 4;
  const int* rp = rp4 + 3*(n+1);
  int s0 = rp[node], s1 = rp[node+1];
  float ssum = 0.f, acc = 0.f;
  for (int j = s0; j < s1; j++){
    int packed = idxh[j];
    float w = wbuf[j*6 + h];
    ssum += w;
    acc  += w * Vb[(size_t)packed*96 + lane];
  }
  float x = (s1 > s0) ? acc/ssum : 0.f;
  gbuf[(size_t)node*96 + lane] = 0.5f*x*(1.f + erff(x*0.70710678118654752f));
}

// ---------------- final linear ----------------
__global__ void k_final_lin(const float* __restrict__ h, const float* __restrict__ w,
                            const float* __restrict__ b, float* __restrict__ out, int N){
  int i = blockIdx.x*TPB + threadIdx.x;
  if (i >= N) return;
  const float4* hr = reinterpret_cast<const float4*>(h + (size_t)i*96);
  const float4* wr = reinterpret_cast<const float4*>(w);
  float acc = 0.f;
  #pragma unroll
  for (int c = 0; c < 24; c++){
    float4 a = hr[c], q = wr[c];
    acc += a.x*q.x + a.y*q.y + a.z*q.z + a.w*q.w;
  }
  out[i] = acc + b[0];
}

// =====================================================================
extern "C" void kernel_launch(void* const* d_in, const int* in_sizes, int n_in,
                              void* d_out, int out_size, void* d_ws, size_t ws_size,
                              hipStream_t stream){
  const float* x        = (const float*)d_in[0];
  const int*   ei       = (const int*)  d_in[1];
  const float* gat0_W   = (const float*)d_in[2];
  const float* gat0_att = (const float*)d_in[3];
  const float* gat0_b   = (const float*)d_in[4];
  const float* gat_W    = (const float*)d_in[5];
  const float* gat_att  = (const float*)d_in[6];
  const float* gat_b    = (const float*)d_in[7];
  const float* bn_g     = (const float*)d_in[8];
  const float* bn_b     = (const float*)d_in[9];
  const float* kqv_W    = (const float*)d_in[10];
  const float* kqv_b    = (const float*)d_in[11];
  const float* a_rel    = (const float*)d_in[12];
  const float* m_rel    = (const float*)d_in[13];
  const float* p_rel    = (const float*)d_in[14];
  const float* hout_W   = (const float*)d_in[15];
  const float* hout_b   = (const float*)d_in[16];
  const float* skip     = (const float*)d_in[17];
  const float* proj_W   = (const float*)d_in[18];
  const float* proj_b   = (const float*)d_in[19];
  const float* lin_W    = (const float*)d_in[20];
  const float* lin_b    = (const float*)d_in[21];
  float* out = (float*)d_out;

  const int N = in_sizes[0] / 32;
  const int E = in_sizes[1] / 6;
  const int EN = E + N;
  const size_t NH = (size_t)N * 96;
  const int nh = (int)NH;
  const float inv_n = 1.f / (float)N;

  // ---- workspace layout (floats, then ints) ----
  float* f = (float*)d_ws;
  float* h_buf = f;  f += NH;
  float* pre   = f;  f += NH;        // also aliased as wbuf_gat / wbuf_hgt (phase A->B window)
  float* b3a   = f;  f += 3*NH;      // hp (GAT) | Kb (HGT)
  float* b3b   = f;  f += 3*NH;      // per-rel GAT out | Vb (HGT)
  float* b3c   = f;  f += 3*NH;      // qkv (HGT)
  float* aux   = f;  f += NH;        // injection | gelu(agg)
  float* asrc  = f;  f += (size_t)3*N*2;
  float* adst  = f;  f += (size_t)3*N*2;
  float* stats = f;  f += 6*192;     // 6 BN slots of (sum[96], sumsq[96])
  int* ip = (int*)f;
  int* cnt     = ip;  ip += 4*N;
  int* rowptr  = ip;  ip += 4*(N+1);
  int* cursor  = ip;  ip += 4*N;
  int* idx_gat     = ip;  ip += 3*EN;
  int* idx_gat_dst = ip;  ip += 3*EN;
  int* idx_hgt     = ip;  ip += 3*E;
  int* idx_hgt_dst = ip;  ip += 3*E;
  float* wbuf = pre;                 // 3*EN*2 = 720k and 3E*6 = 1.8M floats <= NH

  auto g1 = [](int n){ return dim3((n + TPB - 1)/TPB); };
  const int gx = (N + 95)/96;                 // GEMM row-tiles
  const dim3 gg(gx, 3);                       // 3-matrix GEMM grid
  const dim3 g1m(gx, 1);                      // 1-matrix GEMM grid
  const int cs_blocks = (nh + TPB*8 - 1)/(TPB*8);
  const int gat_blocks = (3*N + 3)/4;         // 4 groups of 96 per 384-block
  const int hgt_blocks = (N + 3)/4;

  // ---- CSR build + stats zero ----
  hipMemsetAsync(stats, 0, 6*192*sizeof(float), stream);
  k_init_cnt<<<g1(4*N),     TPB, 0, stream>>>(cnt, N);
  k_count   <<<g1(3*E),     TPB, 0, stream>>>(ei, cnt, N, E);
  k_scan4   <<<4,          1024, 0, stream>>>(cnt, rowptr, cursor, N);
  k_scatter <<<g1(3*E+3*N), TPB, 0, stream>>>(ei, cursor, idx_gat, idx_gat_dst,
                                              idx_hgt, idx_hgt_dst, N, E);

  auto run_hgt = [&](int idx, int bnidx){
    k_gemm_t  <<<gg, GTPB, 0, stream>>>(h_buf, kqv_W + (size_t)idx*3*96*96, kqv_b + idx*3*96, b3c, N, 96);
    k_kv      <<<g1(3*nh), TPB, 0, stream>>>(b3c, b3c + 2*NH,
                                             a_rel + (size_t)idx*3*6*256,
                                             m_rel + (size_t)idx*3*6*256, b3a, b3b, N);
    k_hgt_w   <<<g1(3*E*6), TPB, 0, stream>>>(b3c, b3a, p_rel + idx*18, idx_hgt, idx_hgt_dst, wbuf, N, 3*E);
    k_hgt_agg3<<<hgt_blocks, ATPB, 0, stream>>>(wbuf, b3b, rowptr, idx_hgt, aux, N);
    k_gemm_t  <<<g1m, GTPB, 0, stream>>>(aux, hout_W + (size_t)idx*96*96, hout_b + idx*96, pre, N, 96);
    k_mix_stats<<<cs_blocks, TPB, 0, stream>>>(pre, h_buf, skip + idx, stats + bnidx*192, nh);
    k_apply2  <<<g1(nh), TPB, 0, stream>>>(h_buf, pre, stats + bnidx*192,
                                           bn_g + bnidx*96, bn_b + bnidx*96, nullptr, 1, nh, inv_n);
  };

  // ---- GAT layer 0 (input dim 32, no residual) ----
  k_gemm_t       <<<gg, GTPB, 0, stream>>>(x, gat0_W, nullptr, b3a, N, 32);
  k_attdots      <<<g1(3*N), TPB, 0, stream>>>(b3a, gat0_att, asrc, adst, N);
  k_gat_w        <<<g1(3*EN), TPB, 0, stream>>>(asrc, adst, idx_gat, idx_gat_dst, wbuf, N, EN);
  k_gat_agg3     <<<gat_blocks, ATPB, 0, stream>>>(wbuf, b3a, rowptr, idx_gat, b3b, N, EN);
  k_combine_stats<<<cs_blocks, TPB, 0, stream>>>(b3b, gat0_b, pre, stats, nh);
  k_apply2       <<<g1(nh), TPB, 0, stream>>>(h_buf, pre, stats, bn_g, bn_b, nullptr, 0, nh, inv_n);

  // ---- GAT layers 1..3 ----
  for (int i = 0; i < 3; i++){
    int li = i + 1;
    int bnidx = 1 + i;
    k_gemm_t       <<<gg, GTPB, 0, stream>>>(h_buf, gat_W + (size_t)i*3*96*96, nullptr, b3a, N, 96);
    k_attdots      <<<g1(3*N), TPB, 0, stream>>>(b3a, gat_att + i*3*192, asrc, adst, N);
    k_gat_w        <<<g1(3*EN), TPB, 0, stream>>>(asrc, adst, idx_gat, idx_gat_dst, wbuf, N, EN);
    k_gat_agg3     <<<gat_blocks, ATPB, 0, stream>>>(wbuf, b3a, rowptr, idx_gat, b3b, N, EN);
    k_combine_stats<<<cs_blocks, TPB, 0, stream>>>(b3b, gat_b + i*3*96, pre, stats + bnidx*192, nh);
    const float* inj = nullptr;
    if (li == 2 || li == 3){
      k_gemm_t<<<g1m, GTPB, 0, stream>>>(x, proj_W + (size_t)(li-2)*32*96, proj_b + (li-2)*96, aux, N, 32);
      inj = aux;
    }
    k_apply2<<<g1(nh), TPB, 0, stream>>>(h_buf, pre, stats + bnidx*192,
                                         bn_g + bnidx*96, bn_b + bnidx*96, inj, 1, nh, inv_n);
    if (li == 1) run_hgt(0, 4);
  }
  run_hgt(1, 5);

  k_final_lin<<<g1(N), TPB, 0, stream>>>(h_buf, lin_W, lin_b, out, N);
}

// Round 5
// 1051.135 us; speedup vs baseline: 1.1751x; 1.1747x over previous
//
#include <hip/hip_runtime.h>
#include <math.h>

#define TPB 256

__device__ __forceinline__ float lrelu(float x){ return x > 0.f ? x : 0.2f*x; }

// ---------------- CSR build (graph constant across layers) ----------------
__global__ void k_init_cnt(int* __restrict__ cnt, int N){
  int t = blockIdx.x*TPB + threadIdx.x;
  if (t < 4*N) cnt[t] = (t < 3*N) ? 1 : 0;  // GAT counts start at 1 (self-loop)
}

__global__ void k_count(const int* __restrict__ ei, int* __restrict__ cnt, int N, int E){
  int t = blockIdx.x*TPB + threadIdx.x;
  if (t >= 3*E) return;
  int r = t / E, e = t - r*E;
  int dst = ei[(r*2+1)*E + e];
  atomicAdd(&cnt[r*N + dst], 1);
  atomicAdd(&cnt[3*N + dst], 1);
}

// scan + cursor init fused
__global__ void k_scan4(const int* __restrict__ cnt, int* __restrict__ rp,
                        int* __restrict__ cur, int N){
  __shared__ int sh[1024];
  __shared__ int carry;
  int a = blockIdx.x;
  const int* c = cnt + a*N;
  int* r = rp + a*(N+1);
  if (threadIdx.x == 0) carry = 0;
  __syncthreads();
  for (int base = 0; base < N; base += 1024){
    int idx = base + threadIdx.x;
    int v = (idx < N) ? c[idx] : 0;
    sh[threadIdx.x] = v;
    __syncthreads();
    for (int off = 1; off < 1024; off <<= 1){
      int t = (threadIdx.x >= off) ? sh[threadIdx.x - off] : 0;
      __syncthreads();
      sh[threadIdx.x] += t;
      __syncthreads();
    }
    if (idx < N){
      int ex = carry + sh[threadIdx.x] - v;   // exclusive
      r[idx] = ex;
      cur[a*N + idx] = ex;
    }
    __syncthreads();
    if (threadIdx.x == 0) carry += sh[1023];
    __syncthreads();
  }
  if (threadIdx.x == 0) r[N] = carry;
}

__global__ void k_scatter(const int* __restrict__ ei, int* __restrict__ cur,
                          int* __restrict__ idx_gat,
                          int* __restrict__ idx_hgt, int* __restrict__ idx_hgt_dst,
                          int N, int E){
  int t = blockIdx.x*TPB + threadIdx.x;
  int EN = E + N;
  if (t < 3*E){
    int r = t / E, e = t - r*E;
    int src = ei[(r*2)*E + e];
    int dst = ei[(r*2+1)*E + e];
    int pg = atomicAdd(&cur[r*N + dst], 1);
    idx_gat[r*EN + pg] = src;
    int ph = atomicAdd(&cur[3*N + dst], 1);
    idx_hgt[ph] = r*N + src;           // packed (rel,src)
    idx_hgt_dst[ph] = dst;
  } else if (t < 3*E + 3*N){
    int tt = t - 3*E;
    int r = tt / N, i = tt - r*N;
    int pg = atomicAdd(&cur[r*N + i], 1);
    idx_gat[r*EN + pg] = i;            // self loop
  }
}

// ---------------- LDS-tiled dense GEMM: C[mat] = A @ W[mat] (+ bias) ----------------
#define GTPB 192
__global__ __launch_bounds__(GTPB) void k_gemm_t(const float* __restrict__ A,
                        const float* __restrict__ W,
                        const float* __restrict__ bias, float* __restrict__ C,
                        int n, int K){
  __shared__ float Wl[96*96];
  int mat = blockIdx.y;
  const float4* Wm4 = reinterpret_cast<const float4*>(W + (size_t)mat*K*96);
  for (int idx = threadIdx.x; idx < K*24; idx += GTPB)
    reinterpret_cast<float4*>(Wl)[idx] = Wm4[idx];
  __syncthreads();

  int cg = threadIdx.x % 12;
  int rg = threadIdx.x / 12;     // 0..15
  int c0 = cg*8;
  int r0 = blockIdx.x*96 + rg*6;

  float acc[6][8];
  #pragma unroll
  for (int u = 0; u < 6; u++)
    #pragma unroll
    for (int c = 0; c < 8; c++) acc[u][c] = 0.f;

  for (int k = 0; k < K; k += 4){
    float4 a[6];
    #pragma unroll
    for (int u = 0; u < 6; u++){
      int r = r0 + u;
      a[u] = (r < n) ? *reinterpret_cast<const float4*>(A + (size_t)r*K + k)
                     : make_float4(0.f,0.f,0.f,0.f);
    }
    #pragma unroll
    for (int kk = 0; kk < 4; kk++){
      float4 w0 = *reinterpret_cast<const float4*>(Wl + (k+kk)*96 + c0);
      float4 w1 = *reinterpret_cast<const float4*>(Wl + (k+kk)*96 + c0 + 4);
      float wv0 = w0.x, wv1 = w0.y, wv2 = w0.z, wv3 = w0.w;
      float wv4 = w1.x, wv5 = w1.y, wv6 = w1.z, wv7 = w1.w;
      #pragma unroll
      for (int u = 0; u < 6; u++){
        float av = (kk==0) ? a[u].x : (kk==1) ? a[u].y : (kk==2) ? a[u].z : a[u].w;
        acc[u][0] += av*wv0; acc[u][1] += av*wv1; acc[u][2] += av*wv2; acc[u][3] += av*wv3;
        acc[u][4] += av*wv4; acc[u][5] += av*wv5; acc[u][6] += av*wv6; acc[u][7] += av*wv7;
      }
    }
  }

  float b[8];
  if (bias){
    const float* bp = bias + mat*96 + c0;
    #pragma unroll
    for (int c = 0; c < 8; c++) b[c] = bp[c];
  } else {
    #pragma unroll
    for (int c = 0; c < 8; c++) b[c] = 0.f;
  }
  #pragma unroll
  for (int u = 0; u < 6; u++){
    int r = r0 + u;
    if (r < n){
      float* Cr = C + (size_t)mat*n*96 + (size_t)r*96 + c0;
      float4 o0 = make_float4(acc[u][0]+b[0], acc[u][1]+b[1], acc[u][2]+b[2], acc[u][3]+b[3]);
      float4 o1 = make_float4(acc[u][4]+b[4], acc[u][5]+b[5], acc[u][6]+b[6], acc[u][7]+b[7]);
      reinterpret_cast<float4*>(Cr)[0] = o0;
      reinterpret_cast<float4*>(Cr)[1] = o1;
    }
  }
}

// ---------------- GAT attention dots: a_src/a_dst [3,N,2] ----------------
__global__ void k_attdots(const float* __restrict__ hp, const float* __restrict__ att,
                          float* __restrict__ asrc, float* __restrict__ adst, int n){
  int t = blockIdx.x*TPB + threadIdx.x;
  if (t >= 3*n) return;
  int r = t / n;                       // t == r*n+i
  const float* row = hp + (size_t)t*96;
  const float* ap  = att + r*192;      // [2,2,48] per relation
  #pragma unroll
  for (int h = 0; h < 2; h++){
    float s = 0.f, d = 0.f;
    #pragma unroll 8
    for (int dd = 0; dd < 48; dd++){
      float v = row[h*48 + dd];
      s += v * ap[h*48 + dd];
      d += v * ap[96 + h*48 + dd];
    }
    asrc[t*2 + h] = s;
    adst[t*2 + h] = d;
  }
}

// ---------------- GAT fused: wave per node; 3 relations; weights + gather + combine + bias ----
__global__ __launch_bounds__(TPB) void k_gat_fused(const float* __restrict__ asrc,
                        const float* __restrict__ adst, const float* __restrict__ hp,
                        const int* __restrict__ rowptr, const int* __restrict__ idxg,
                        const float* __restrict__ b3, float* __restrict__ pre,
                        int n, int EN){
  int wid = (blockIdx.x*TPB + threadIdx.x) >> 6;   // wave id = node
  if (wid >= n) return;
  int lane = threadIdx.x & 63;
  float comb_a = 0.f, comb_b = 0.f;
  #pragma unroll
  for (int r = 0; r < 3; r++){
    const int* rp = rowptr + r*(n+1);
    int s0 = rp[wid], s1 = rp[wid+1];
    const int* ix = idxg + (size_t)r*EN;
    const float2* as2 = reinterpret_cast<const float2*>(asrc) + (size_t)r*n;
    float2 ad = (reinterpret_cast<const float2*>(adst) + (size_t)r*n)[wid];
    const float* hpb = hp + (size_t)r*n*96;
    float acc_a = 0.f, acc_b = 0.f, ss0 = 0.f, ss1 = 0.f;
    for (int base = s0; base < s1; base += 64){
      int cnt = min(64, s1 - base);
      int src_l = 0; float w0_l = 0.f, w1_l = 0.f;
      if (lane < cnt){
        src_l = ix[base + lane];
        float2 av = as2[src_l];
        w0_l = __expf(fminf(lrelu(av.x + ad.x), 80.f));
        w1_l = __expf(fminf(lrelu(av.y + ad.y), 80.f));
      }
      for (int j = 0; j < cnt; j++){
        int   src = __shfl(src_l, j);
        float w0  = __shfl(w0_l, j);
        float w1  = __shfl(w1_l, j);
        const float* row = hpb + (size_t)src*96;
        float va = row[lane];
        float vb = (lane < 32) ? row[64 + lane] : 0.f;
        float wa = (lane < 48) ? w0 : w1;
        acc_a += wa*va;
        acc_b += w1*vb;
        ss0 += w0; ss1 += w1;
      }
    }
    comb_a += acc_a / ((lane < 48) ? ss0 : ss1);   // self-loop => non-empty
    comb_b += acc_b / ss1;
  }
  comb_a += b3[lane] + b3[96 + lane] + b3[192 + lane];
  float* pr = pre + (size_t)wid*96;
  pr[lane] = comb_a;
  if (lane < 32){
    comb_b += b3[64 + lane] + b3[160 + lane] + b3[256 + lane];
    pr[64 + lane] = comb_b;
  }
}

// ---------------- BN stats over pre: grid-stride sum/sumsq ----------------
__global__ void k_stats(const float* __restrict__ pre, float* __restrict__ stats, int total){
  __shared__ float s1[96], s2[96];
  if (threadIdx.x < 96){ s1[threadIdx.x] = 0.f; s2[threadIdx.x] = 0.f; }
  __syncthreads();
  int idx0 = blockIdx.x*TPB*8 + threadIdx.x;
  for (int it = 0; it < 8; it++){
    int idx = idx0 + it*TPB;
    if (idx < total){
      int c = idx % 96;
      float v = pre[idx];
      atomicAdd(&s1[c], v);
      atomicAdd(&s2[c], v*v);
    }
  }
  __syncthreads();
  if (threadIdx.x < 96){
    atomicAdd(&stats[threadIdx.x], s1[threadIdx.x]);
    atomicAdd(&stats[96 + threadIdx.x], s2[threadIdx.x]);
  }
}

// ---------------- HGT skip-mix in place + BN stats ----------------
__global__ void k_mix_stats(float* __restrict__ pre, const float* __restrict__ h,
                            const float* __restrict__ skip, float* __restrict__ stats, int total){
  __shared__ float s1[96], s2[96];
  if (threadIdx.x < 96){ s1[threadIdx.x] = 0.f; s2[threadIdx.x] = 0.f; }
  __syncthreads();
  float sk = 1.f / (1.f + expf(-skip[0]));
  int idx0 = blockIdx.x*TPB*8 + threadIdx.x;
  for (int it = 0; it < 8; it++){
    int idx = idx0 + it*TPB;
    if (idx < total){
      int c = idx % 96;
      float v = sk*pre[idx] + (1.f - sk)*h[idx];
      pre[idx] = v;
      atomicAdd(&s1[c], v);
      atomicAdd(&s2[c], v*v);
    }
  }
  __syncthreads();
  if (threadIdx.x < 96){
    atomicAdd(&stats[threadIdx.x], s1[threadIdx.x]);
    atomicAdd(&stats[96 + threadIdx.x], s2[threadIdx.x]);
  }
}

// ---------------- apply with inline BN finalize: h = lrelu(res*h + bn(pre) + inj) ----------------
__global__ void k_apply2(float* __restrict__ h, const float* __restrict__ pre,
                         const float* __restrict__ stats, const float* __restrict__ gamma,
                         const float* __restrict__ beta, const float* __restrict__ inj,
                         int res, int total, float inv_n){
  int idx = blockIdx.x*TPB + threadIdx.x;
  if (idx >= total) return;
  int c = idx % 96;
  float mean = stats[c] * inv_n;
  float var  = stats[96 + c] * inv_n - mean*mean;
  float sc   = gamma[c] * rsqrtf(var + 1e-5f);
  float sh   = beta[c] - mean*sc;
  float v = sc*pre[idx] + sh;
  if (inj) v += inj[idx];
  if (res) v += h[idx];
  h[idx] = lrelu(v);
}

// ---------------- HGT per-node K/V transforms: K_r = k·a_rel, V_r = v·m_rel ----------------
__global__ void k_kv(const float* __restrict__ kin, const float* __restrict__ vin,
                     const float* __restrict__ arel, const float* __restrict__ mrel,
                     float* __restrict__ Kb, float* __restrict__ Vb, int n){
  int t = blockIdx.x*TPB + threadIdx.x;
  if (t >= 3*n*96) return;
  int c = t % 96;
  int i = (t / 96) % n;
  int r = t / (96*n);
  int hh = c >> 4, f = c & 15;
  const float* kr = kin + (size_t)i*96 + hh*16;
  const float* vr = vin + (size_t)i*96 + hh*16;
  const float* ar = arel + (size_t)((r*6 + hh)*16)*16 + f;
  const float* mr = mrel + (size_t)((r*6 + hh)*16)*16 + f;
  float ka = 0.f, va = 0.f;
  #pragma unroll
  for (int d = 0; d < 16; d++){
    ka += kr[d] * ar[d*16];
    va += vr[d] * mr[d*16];
  }
  Kb[t] = ka;   // t == (r*n+i)*96+c
  Vb[t] = va;
}

// ---------------- HGT phase A: per-(slot,head) edge weights ----------------
__global__ void k_hgt_w(const float* __restrict__ qkv, const float* __restrict__ Kb,
                        const float* __restrict__ prel, const int* __restrict__ idxh,
                        const int* __restrict__ idxh_dst, float* __restrict__ wbuf,
                        int n, int totE){
  int t = blockIdx.x*TPB + threadIdx.x;
  if (t >= totE*6) return;
  int slot = t / 6, h = t - slot*6;
  int packed = idxh[slot];
  int dst = idxh_dst[slot];
  int r = (packed >= 2*n) ? 2 : (packed >= n ? 1 : 0);
  float pp = 0.25f * prel[r*6 + h];
  const float4* kp = reinterpret_cast<const float4*>(Kb + (size_t)packed*96 + h*16);
  const float4* qp = reinterpret_cast<const float4*>(qkv + (size_t)n*96 + (size_t)dst*96 + h*16);
  float dot = 0.f;
  #pragma unroll
  for (int w = 0; w < 4; w++){
    float4 kv = kp[w], qv = qp[w];
    dot += kv.x*qv.x + kv.y*qv.y + kv.z*qv.z + kv.w*qv.w;
  }
  wbuf[t] = __expf(fminf(dot*pp, 80.f));
}

// ---------------- HGT fused gather: wave per node; shfl-staged; + GELU ----------------
__global__ __launch_bounds__(TPB) void k_hgt_fused(const float* __restrict__ wbuf,
                        const float* __restrict__ Vb, const int* __restrict__ rp4,
                        const int* __restrict__ idxh, float* __restrict__ gbuf, int n){
  int wid = (blockIdx.x*TPB + threadIdx.x) >> 6;
  if (wid >= n) return;
  int lane = threadIdx.x & 63;
  const int* rp = rp4 + 3*(n+1);
  int s0 = rp[wid], s1 = rp[wid+1];
  int ha = lane >> 4;                         // head for col=lane (0..3)
  float acc_a = 0.f, acc_b = 0.f, ss_a = 0.f, ss_b = 0.f;
  for (int base = s0; base < s1; base += 64){
    int cnt = min(64, s1 - base);
    int pk = 0; float w0=0.f,w1=0.f,w2=0.f,w3=0.f,w4=0.f,w5=0.f;
    if (lane < cnt){
      int slot = base + lane;
      pk = idxh[slot];
      const float2* wp = reinterpret_cast<const float2*>(wbuf + (size_t)slot*6);
      float2 p0 = wp[0], p1 = wp[1], p2 = wp[2];
      w0=p0.x; w1=p0.y; w2=p1.x; w3=p1.y; w4=p2.x; w5=p2.y;
    }
    for (int j = 0; j < cnt; j++){
      int packed = __shfl(pk, j);
      float b0=__shfl(w0,j), b1=__shfl(w1,j), b2=__shfl(w2,j),
            b3v=__shfl(w3,j), b4=__shfl(w4,j), b5=__shfl(w5,j);
      const float* row = Vb + (size_t)packed*96;
      float va = row[lane];
      float vb = (lane < 32) ? row[64 + lane] : 0.f;
      float wa = (ha==0) ? b0 : ((ha==1) ? b1 : ((ha==2) ? b2 : b3v));
      float wb = ((lane >> 4) == 0) ? b4 : b5;   // head 4/5 for cols 64..95
      acc_a += wa*va; ss_a += wa;
      acc_b += wb*vb; ss_b += wb;
    }
  }
  float xa = (s1 > s0) ? acc_a/ss_a : 0.f;
  float* gb = gbuf + (size_t)wid*96;
  gb[lane] = 0.5f*xa*(1.f + erff(xa*0.70710678118654752f));
  if (lane < 32){
    float xb = (s1 > s0) ? acc_b/ss_b : 0.f;
    gb[64 + lane] = 0.5f*xb*(1.f + erff(xb*0.70710678118654752f));
  }
}

// ---------------- final linear ----------------
__global__ void k_final_lin(const float* __restrict__ h, const float* __restrict__ w,
                            const float* __restrict__ b, float* __restrict__ out, int N){
  int i = blockIdx.x*TPB + threadIdx.x;
  if (i >= N) return;
  const float4* hr = reinterpret_cast<const float4*>(h + (size_t)i*96);
  const float4* wr = reinterpret_cast<const float4*>(w);
  float acc = 0.f;
  #pragma unroll
  for (int c = 0; c < 24; c++){
    float4 a = hr[c], q = wr[c];
    acc += a.x*q.x + a.y*q.y + a.z*q.z + a.w*q.w;
  }
  out[i] = acc + b[0];
}

// =====================================================================
extern "C" void kernel_launch(void* const* d_in, const int* in_sizes, int n_in,
                              void* d_out, int out_size, void* d_ws, size_t ws_size,
                              hipStream_t stream){
  const float* x        = (const float*)d_in[0];
  const int*   ei       = (const int*)  d_in[1];
  const float* gat0_W   = (const float*)d_in[2];
  const float* gat0_att = (const float*)d_in[3];
  const float* gat0_b   = (const float*)d_in[4];
  const float* gat_W    = (const float*)d_in[5];
  const float* gat_att  = (const float*)d_in[6];
  const float* gat_b    = (const float*)d_in[7];
  const float* bn_g     = (const float*)d_in[8];
  const float* bn_b     = (const float*)d_in[9];
  const float* kqv_W    = (const float*)d_in[10];
  const float* kqv_b    = (const float*)d_in[11];
  const float* a_rel    = (const float*)d_in[12];
  const float* m_rel    = (const float*)d_in[13];
  const float* p_rel    = (const float*)d_in[14];
  const float* hout_W   = (const float*)d_in[15];
  const float* hout_b   = (const float*)d_in[16];
  const float* skip     = (const float*)d_in[17];
  const float* proj_W   = (const float*)d_in[18];
  const float* proj_b   = (const float*)d_in[19];
  const float* lin_W    = (const float*)d_in[20];
  const float* lin_b    = (const float*)d_in[21];
  float* out = (float*)d_out;

  const int N = in_sizes[0] / 32;
  const int E = in_sizes[1] / 6;
  const int EN = E + N;
  const size_t NH = (size_t)N * 96;
  const int nh = (int)NH;
  const float inv_n = 1.f / (float)N;

  // ---- workspace layout (floats, then ints) ----
  float* f = (float*)d_ws;
  float* h_buf = f;  f += NH;
  float* pre   = f;  f += NH;        // aliased as wbuf (HGT phase A->B window)
  float* b3a   = f;  f += 3*NH;      // hp (GAT) | Kb (HGT)
  float* b3b   = f;  f += 3*NH;      // Vb (HGT)
  float* b3c   = f;  f += 3*NH;      // qkv (HGT)
  float* aux   = f;  f += NH;        // injection | gelu(agg)
  float* asrc  = f;  f += (size_t)3*N*2;
  float* adst  = f;  f += (size_t)3*N*2;
  float* stats = f;  f += 6*192;     // 6 BN slots of (sum[96], sumsq[96])
  int* ip = (int*)f;
  int* cnt     = ip;  ip += 4*N;
  int* rowptr  = ip;  ip += 4*(N+1);
  int* cursor  = ip;  ip += 4*N;
  int* idx_gat     = ip;  ip += 3*EN;
  int* idx_hgt     = ip;  ip += 3*E;
  int* idx_hgt_dst = ip;  ip += 3*E;
  float* wbuf = pre;                 // 3E*6 = 1.8M floats <= NH

  auto g1 = [](int n){ return dim3((n + TPB - 1)/TPB); };
  const int gx = (N + 95)/96;                 // GEMM row-tiles
  const dim3 gg(gx, 3);                       // 3-matrix GEMM grid
  const dim3 g1m(gx, 1);                      // 1-matrix GEMM grid
  const int cs_blocks = (nh + TPB*8 - 1)/(TPB*8);
  const int wave_blocks = (N + 3)/4;          // 4 waves (nodes) per 256-block

  // ---- CSR build + stats zero ----
  hipMemsetAsync(stats, 0, 6*192*sizeof(float), stream);
  k_init_cnt<<<g1(4*N),     TPB, 0, stream>>>(cnt, N);
  k_count   <<<g1(3*E),     TPB, 0, stream>>>(ei, cnt, N, E);
  k_scan4   <<<4,          1024, 0, stream>>>(cnt, rowptr, cursor, N);
  k_scatter <<<g1(3*E+3*N), TPB, 0, stream>>>(ei, cursor, idx_gat, idx_hgt, idx_hgt_dst, N, E);

  auto run_hgt = [&](int idx, int bnidx){
    k_gemm_t   <<<gg, GTPB, 0, stream>>>(h_buf, kqv_W + (size_t)idx*3*96*96, kqv_b + idx*3*96, b3c, N, 96);
    k_kv       <<<g1(3*nh), TPB, 0, stream>>>(b3c, b3c + 2*NH,
                                              a_rel + (size_t)idx*3*6*256,
                                              m_rel + (size_t)idx*3*6*256, b3a, b3b, N);
    k_hgt_w    <<<g1(3*E*6), TPB, 0, stream>>>(b3c, b3a, p_rel + idx*18, idx_hgt, idx_hgt_dst, wbuf, N, 3*E);
    k_hgt_fused<<<wave_blocks, TPB, 0, stream>>>(wbuf, b3b, rowptr, idx_hgt, aux, N);
    k_gemm_t   <<<g1m, GTPB, 0, stream>>>(aux, hout_W + (size_t)idx*96*96, hout_b + idx*96, pre, N, 96);
    k_mix_stats<<<cs_blocks, TPB, 0, stream>>>(pre, h_buf, skip + idx, stats + bnidx*192, nh);
    k_apply2   <<<g1(nh), TPB, 0, stream>>>(h_buf, pre, stats + bnidx*192,
                                            bn_g + bnidx*96, bn_b + bnidx*96, nullptr, 1, nh, inv_n);
  };

  // ---- GAT layer 0 (input dim 32, no residual) ----
  k_gemm_t   <<<gg, GTPB, 0, stream>>>(x, gat0_W, nullptr, b3a, N, 32);
  k_attdots  <<<g1(3*N), TPB, 0, stream>>>(b3a, gat0_att, asrc, adst, N);
  k_gat_fused<<<wave_blocks, TPB, 0, stream>>>(asrc, adst, b3a, rowptr, idx_gat, gat0_b, pre, N, EN);
  k_stats    <<<cs_blocks, TPB, 0, stream>>>(pre, stats, nh);
  k_apply2   <<<g1(nh), TPB, 0, stream>>>(h_buf, pre, stats, bn_g, bn_b, nullptr, 0, nh, inv_n);

  // ---- GAT layers 1..3 ----
  for (int i = 0; i < 3; i++){
    int li = i + 1;
    int bnidx = 1 + i;
    k_gemm_t   <<<gg, GTPB, 0, stream>>>(h_buf, gat_W + (size_t)i*3*96*96, nullptr, b3a, N, 96);
    k_attdots  <<<g1(3*N), TPB, 0, stream>>>(b3a, gat_att + i*3*192, asrc, adst, N);
    k_gat_fused<<<wave_blocks, TPB, 0, stream>>>(asrc, adst, b3a, rowptr, idx_gat, gat_b + i*3*96, pre, N, EN);
    k_stats    <<<cs_blocks, TPB, 0, stream>>>(pre, stats + bnidx*192, nh);
    const float* inj = nullptr;
    if (li == 2 || li == 3){
      k_gemm_t<<<g1m, GTPB, 0, stream>>>(x, proj_W + (size_t)(li-2)*32*96, proj_b + (li-2)*96, aux, N, 32);
      inj = aux;
    }
    k_apply2<<<g1(nh), TPB, 0, stream>>>(h_buf, pre, stats + bnidx*192,
                                         bn_g + bnidx*96, bn_b + bnidx*96, inj, 1, nh, inv_n);
    if (li == 1) run_hgt(0, 4);
  }
  run_hgt(1, 5);

  k_final_lin<<<g1(N), TPB, 0, stream>>>(h_buf, lin_W, lin_b, out, N);
}